// Round 8
// baseline (9216.846 us; speedup 1.0000x reference)
//
#include <hip/hip_runtime.h>

typedef short bf16x8 __attribute__((ext_vector_type(8)));
typedef float f32x4 __attribute__((ext_vector_type(4)));

__device__ __forceinline__ unsigned pack2bf(float a, float b) {
  union { float f; unsigned u; } x, y;
  x.f = a; y.f = b;
  unsigned ra = (x.u + 0x7FFFu + ((x.u >> 16) & 1u)) >> 16;
  unsigned rb = (y.u + 0x7FFFu + ((y.u >> 16) & 1u)) & 0xFFFF0000u;
  return ra | rb;
}
__device__ __forceinline__ unsigned short bfu(float f) {
  union { float f; unsigned u; } v; v.f = f;
  return (unsigned short)((v.u + 0x7FFFu + ((v.u >> 16) & 1u)) >> 16);
}
__device__ __forceinline__ float sigf(float x) { return 1.f / (1.f + __expf(-x)); }

#define KB 64
#define LDSP 72

// ---------------- xg GEMM (proven rounds 1-5) ----------------
__global__ __launch_bounds__(256) void gemm_bt(
    const float* __restrict__ A0, size_t a_bstride,
    const float* __restrict__ W,
    const float* __restrict__ bias,
    float* __restrict__ out, size_t o_bstride,
    int Mvalid)
{
  __shared__ unsigned short As[64][LDSP];
  __shared__ unsigned short Bs[64][LDSP];
  const int tid = threadIdx.x;
  const int g0 = blockIdx.x * 64;
  const float* Ab = A0 + (size_t)blockIdx.y * a_bstride;
  float* outb = out + (size_t)blockIdx.y * o_bstride;

  const int srow = tid >> 2;
  const int scol = (tid & 3) << 4;
  const int wv = tid >> 6;
  const int lane = tid & 63;
  const int wr = wv >> 1, wc = wv & 1;
  const int lrow = lane & 15;
  const int lk = (lane >> 4) << 3;

  f32x4 acc[2][2];
#pragma unroll
  for (int i = 0; i < 2; ++i)
#pragma unroll
    for (int j = 0; j < 2; ++j)
      acc[i][j] = (f32x4){0.f, 0.f, 0.f, 0.f};

  const float* Aptr = Ab + (size_t)srow * 768 + scol;
  const float* Bptr = W + ((size_t)(g0 + srow)) * 768 + scol;
  const bool aval = srow < Mvalid;

  for (int k0 = 0; k0 < 768; k0 += KB) {
    uint4 ua0, ua1, ub0, ub1;
    if (aval) {
      const float4* qa = (const float4*)(Aptr + k0);
      float4 f0 = qa[0], f1 = qa[1], f2 = qa[2], f3 = qa[3];
      ua0 = make_uint4(pack2bf(f0.x, f0.y), pack2bf(f0.z, f0.w),
                       pack2bf(f1.x, f1.y), pack2bf(f1.z, f1.w));
      ua1 = make_uint4(pack2bf(f2.x, f2.y), pack2bf(f2.z, f2.w),
                       pack2bf(f3.x, f3.y), pack2bf(f3.z, f3.w));
    } else {
      ua0 = make_uint4(0u, 0u, 0u, 0u);
      ua1 = ua0;
    }
    {
      const float4* qb = (const float4*)(Bptr + k0);
      float4 f0 = qb[0], f1 = qb[1], f2 = qb[2], f3 = qb[3];
      ub0 = make_uint4(pack2bf(f0.x, f0.y), pack2bf(f0.z, f0.w),
                       pack2bf(f1.x, f1.y), pack2bf(f1.z, f1.w));
      ub1 = make_uint4(pack2bf(f2.x, f2.y), pack2bf(f2.z, f2.w),
                       pack2bf(f3.x, f3.y), pack2bf(f3.z, f3.w));
    }
    __syncthreads();
    *(uint4*)&As[srow][scol] = ua0;
    *(uint4*)&As[srow][scol + 8] = ua1;
    *(uint4*)&Bs[srow][scol] = ub0;
    *(uint4*)&Bs[srow][scol + 8] = ub1;
    __syncthreads();
#pragma unroll
    for (int kh = 0; kh < 2; ++kh) {
      bf16x8 a0 = *(const bf16x8*)&As[32 * wr + lrow][32 * kh + lk];
      bf16x8 a1 = *(const bf16x8*)&As[32 * wr + 16 + lrow][32 * kh + lk];
      bf16x8 b0 = *(const bf16x8*)&Bs[32 * wc + lrow][32 * kh + lk];
      bf16x8 b1 = *(const bf16x8*)&Bs[32 * wc + 16 + lrow][32 * kh + lk];
      acc[0][0] = __builtin_amdgcn_mfma_f32_16x16x32_bf16(a0, b0, acc[0][0], 0, 0, 0);
      acc[0][1] = __builtin_amdgcn_mfma_f32_16x16x32_bf16(a0, b1, acc[0][1], 0, 0, 0);
      acc[1][0] = __builtin_amdgcn_mfma_f32_16x16x32_bf16(a1, b0, acc[1][0], 0, 0, 0);
      acc[1][1] = __builtin_amdgcn_mfma_f32_16x16x32_bf16(a1, b1, acc[1][1], 0, 0, 0);
    }
  }

  const int lgrp = lane >> 4;
#pragma unroll
  for (int fr = 0; fr < 2; ++fr)
#pragma unroll
    for (int fc = 0; fc < 2; ++fc)
#pragma unroll
      for (int j = 0; j < 4; ++j) {
        int m = 32 * wr + 16 * fr + lgrp * 4 + j;
        int n = 32 * wc + 16 * fc + lrow;
        if (m < Mvalid)
          outb[(size_t)m * 2304 + g0 + n] = acc[fr][fc][j] + bias[g0 + n];
      }
}

// ---------------- persistent recurrent kernel (R5-proven memory ops) ----------------
#define NWG 64
#define NPROD 36
#define EPS 1e-5f
#define INV768 (1.0f / 768.0f)
#define SLOT 24576u  // u32 words per h-history slot (96*64*4)

// R5-proven arrive: syncthreads drains vmcnt, RETURNING relaxed agent RMW.
__device__ __forceinline__ void bar_arrive(unsigned* c) {
  __syncthreads();
  if (threadIdx.x == 0)
    __hip_atomic_fetch_add(c + (blockIdx.x & 7) * 32, 1u,
                           __ATOMIC_RELAXED, __HIP_MEMORY_SCOPE_AGENT);
}
__device__ __forceinline__ void bar_wait(unsigned* c, unsigned tgt) {
  if (threadIdx.x == 0) {
    for (;;) {
      unsigned s = 0;
#pragma unroll
      for (int i = 0; i < 8; ++i)
        s += __hip_atomic_load(c + i * 32, __ATOMIC_RELAXED, __HIP_MEMORY_SCOPE_AGENT);
      if (s >= tgt) break;
      __builtin_amdgcn_s_sleep(1);
    }
  }
  __syncthreads();
}

template <int N>
__device__ __forceinline__ void blk_reduce(float* v, float* lds) {
#pragma unroll
  for (int k = 0; k < N; ++k) {
    float x = v[k];
#pragma unroll
    for (int off = 1; off < 64; off <<= 1) x += __shfl_xor(x, off);
    v[k] = x;
  }
  const int wv = threadIdx.x >> 6;
  const int lane = threadIdx.x & 63;
  if (lane == 0) {
#pragma unroll
    for (int k = 0; k < N; ++k) lds[wv * N + k] = v[k];
  }
  __syncthreads();
#pragma unroll
  for (int k = 0; k < N; ++k)
    v[k] = lds[k] + lds[N + k] + lds[2 * N + k] + lds[3 * N + k];
  __syncthreads();
}

#define WAITV(n) do { asm volatile("s_waitcnt vmcnt(" #n ")" ::: "memory"); \
                      __builtin_amdgcn_sched_barrier(0); } while (0)

// sc0|sc1 coherence-point loads (R5-proven)
#define LD6(buf, kk0) \
  { _Pragma("unroll") for (int q_ = 0; q_ < 6; ++q_) { \
      const unsigned* p_ = hb + (size_t)((kk0) + q_) * 1024u; \
      asm volatile("global_load_dwordx4 %0, %1, off sc0 sc1" : "=v"(buf[q_]) : "v"(p_)); } }

#define MFMA6(buf, kk0) \
  { _Pragma("unroll") for (int q_ = 0; q_ < 6; ++q_) { \
      int kk_ = (kk0) + q_; \
      bf16x8 w0 = *(const bf16x8*)&Wl[la][kk_ * 32 + kb * 8]; \
      bf16x8 w1 = *(const bf16x8*)&Wl[16 + la][kk_ * 32 + kb * 8]; \
      bf16x8 w2 = *(const bf16x8*)&Wl[32 + la][kk_ * 32 + kb * 8]; \
      bf16x8 w3 = *(const bf16x8*)&Wl[48 + la][kk_ * 32 + kb * 8]; \
      acc0 = __builtin_amdgcn_mfma_f32_16x16x32_bf16(buf[q_], w0, acc0, 0, 0, 0); \
      acc1 = __builtin_amdgcn_mfma_f32_16x16x32_bf16(buf[q_], w1, acc1, 0, 0, 0); \
      acc2 = __builtin_amdgcn_mfma_f32_16x16x32_bf16(buf[q_], w2, acc2, 0, 0, 0); \
      acc3 = __builtin_amdgcn_mfma_f32_16x16x32_bf16(buf[q_], w3, acc3, 0, 0, 0); } }

__global__ __launch_bounds__(256, 1) void gru_chunk(
    const float* __restrict__ Whh, const float* __restrict__ bhh,
    const float* __restrict__ lw, const float* __restrict__ lb,
    const float* __restrict__ xg,     // [64][TC][2304]  (includes b_ih)
    int TC,
    const float* __restrict__ hin,    // [64][768] f32
    float* __restrict__ hstate,       // [64][768] f32
    unsigned* __restrict__ hbf32,     // [TC+1][96][64][4] u32 (bf16 pairs)
    float* __restrict__ hg,           // [64][2304] f32 (sc1 exchange)
    unsigned* __restrict__ barA, unsigned* __restrict__ barB,
    float* __restrict__ hfin, int lastflag)
{
  __shared__ unsigned short Wl[64][776];   // producer's 64 gate rows, bf16
  __shared__ float lwl[2304], lbl[2304];
  __shared__ float bhl[64];
  __shared__ float redl[16];

  const int wg = blockIdx.x;
  const int tid = threadIdx.x;
  const int g0w = wg * 64;
  const int lane = tid & 63;
  const int w = tid >> 6;
  const int la = lane & 15;
  const int kb = lane >> 4;
  const int arow = 16 * w + la;

  if (wg < NPROD) {
    for (int r = 0; r < 64; ++r) {
      const float* src = Whh + (size_t)(g0w + r) * 768;
      for (int c = tid; c < 768; c += 256) Wl[r][c] = bfu(src[c]);
    }
    if (tid < 64) bhl[tid] = bhh[g0w + tid];
  }

  const int b = wg;                  // every WG owns batch b's update
  for (int c = tid; c < 2304; c += 256) { lwl[c] = lw[c]; lbl[c] = lb[c]; }
  float hreg[3];
#pragma unroll
  for (int p = 0; p < 3; ++p) hreg[p] = hin[(size_t)b * 768 + tid + (p << 8)];
  {
    // write h-history slot 0 (chunk input state) as packed bf16, sc1 stores
#pragma unroll
    for (int p = 0; p < 3; ++p) {
      int i = tid + (p << 8);
      float other = __shfl_xor(hreg[p], 1);
      if ((tid & 1) == 0) {
        unsigned pk = pack2bf(hreg[p], other);
        __hip_atomic_store(hbf32 + (i >> 3) * 256 + b * 4 + ((i >> 1) & 3), pk,
                           __ATOMIC_RELAXED, __HIP_MEMORY_SCOPE_AGENT);
      }
    }
  }
  bar_arrive(barB);
  bar_wait(barB, NWG);

  for (int tt = 0; tt < TC; ++tt) {
    // ---- phase A (producers): hg[all b][our 64 rows] = h @ Whh^T + bhh ----
    // All 24 A-fragment loads issued up front: ONE exposed IF round trip.
    if (wg < NPROD) {
      const unsigned* hb = hbf32 + (size_t)tt * SLOT + (size_t)((kb * 64 + arow) << 2);
      f32x4 acc0 = (f32x4){0.f, 0.f, 0.f, 0.f}, acc1 = acc0, acc2 = acc0, acc3 = acc0;
      bf16x8 afA[6], afB[6], afC[6], afD[6];
      LD6(afA, 0);
      LD6(afB, 6);
      LD6(afC, 12);
      LD6(afD, 18);
      WAITV(18);
      MFMA6(afA, 0);
      WAITV(12);
      MFMA6(afB, 6);
      WAITV(6);
      MFMA6(afC, 12);
      WAITV(0);
      MFMA6(afD, 18);
#pragma unroll
      for (int j = 0; j < 4; ++j) {
        int bb = 16 * w + kb * 4 + j;
        float* hp = hg + (size_t)bb * 2304 + g0w;
        __hip_atomic_store(hp + la,      acc0[j] + bhl[la],      __ATOMIC_RELAXED, __HIP_MEMORY_SCOPE_AGENT);
        __hip_atomic_store(hp + 16 + la, acc1[j] + bhl[16 + la], __ATOMIC_RELAXED, __HIP_MEMORY_SCOPE_AGENT);
        __hip_atomic_store(hp + 32 + la, acc2[j] + bhl[32 + la], __ATOMIC_RELAXED, __HIP_MEMORY_SCOPE_AGENT);
        __hip_atomic_store(hp + 48 + la, acc3[j] + bhl[48 + la], __ATOMIC_RELAXED, __HIP_MEMORY_SCOPE_AGENT);
      }
    }

    // hoist xg loads (prior-dispatch data, plain cached)
    float xr_[3], xz_[3], xn_[3];
    {
      const float* xgb = xg + ((size_t)b * TC + tt) * 2304;
#pragma unroll
      for (int p = 0; p < 3; ++p) {
        int i = tid + (p << 8);
        xr_[p] = xgb[i];
        xz_[p] = xgb[768 + i];
        xn_[p] = xgb[1536 + i];
      }
    }

    if (wg < NPROD) bar_arrive(barA);
    bar_wait(barA, (unsigned)(tt + 1) * NPROD);

    // ---- phase B (all 64 WGs): direct per-thread hg reads (sc1, coalesced) ----
    {
      float hgv[9];
      const float* hgb = hg + (size_t)b * 2304;
#pragma unroll
      for (int p = 0; p < 9; ++p) {
        const float* pp = hgb + tid + p * 256;
        asm volatile("global_load_dword %0, %1, off sc0 sc1" : "=v"(hgv[p]) : "v"(pp));
      }
      WAITV(0);

      float s1[3], s2[3], hn[3];
      float v4[4] = {0.f, 0.f, 0.f, 0.f};
#pragma unroll
      for (int p = 0; p < 3; ++p) {
        s1[p] = hgv[p] + xr_[p];
        s2[p] = hgv[3 + p] + xz_[p];
        hn[p] = hgv[6 + p];
        v4[0] += s1[p]; v4[1] += s1[p] * s1[p];
        v4[2] += s2[p]; v4[3] += s2[p] * s2[p];
      }
      blk_reduce<4>(v4, redl);
      float mu1 = v4[0] * INV768, rs1 = rsqrtf(v4[1] * INV768 - mu1 * mu1 + EPS);
      float mu2 = v4[2] * INV768, rs2 = rsqrtf(v4[3] * INV768 - mu2 * mu2 + EPS);

      float zq[3], mq[3];
      float v2[2] = {0.f, 0.f};
#pragma unroll
      for (int p = 0; p < 3; ++p) {
        int i = tid + (p << 8);
        float r = sigf((s1[p] - mu1) * rs1 * lwl[i] + lbl[i]);
        zq[p] = sigf((s2[p] - mu2) * rs2 * lwl[768 + i] + lbl[768 + i]);
        mq[p] = xn_[p] + r * hn[p];
        v2[0] += mq[p]; v2[1] += mq[p] * mq[p];
      }
      blk_reduce<2>(v2, redl);
      float mum = v2[0] * INV768, rsm = rsqrtf(v2[1] * INV768 - mum * mum + EPS);

      unsigned* hbslot = hbf32 + (size_t)(tt + 1) * SLOT;
#pragma unroll
      for (int p = 0; p < 3; ++p) {
        int i = tid + (p << 8);
        float n = tanhf((mq[p] - mum) * rsm * lwl[1536 + i] + lbl[1536 + i]);
        float hnew = (1.f - zq[p]) * n + zq[p] * hreg[p];
        hreg[p] = hnew;
        float other = __shfl_xor(hnew, 1);
        if ((tid & 1) == 0) {
          unsigned pk = pack2bf(hnew, other);
          __hip_atomic_store(hbslot + (i >> 3) * 256 + b * 4 + ((i >> 1) & 3), pk,
                             __ATOMIC_RELAXED, __HIP_MEMORY_SCOPE_AGENT);
        }
      }
    }
    bar_arrive(barB);
    bar_wait(barB, (unsigned)(tt + 2) * NWG);
  }

#pragma unroll
  for (int p = 0; p < 3; ++p) {
    int i = tid + (p << 8);
    hstate[(size_t)b * 768 + i] = hreg[p];
    if (lastflag) hfin[(size_t)b * 768 + i] = hreg[p];
  }
}

// ---------------- seq emission: seq = bf16(h_hist) + res ----------------
__global__ __launch_bounds__(256) void seq_emit(
    const unsigned* __restrict__ hbf,  // [TC+1][24576], slots 1..TC
    const float* __restrict__ res,
    float* __restrict__ seq,
    int t0, int TC)
{
  int t = blockIdx.x * 256 + threadIdx.x;   // [TC][64][96][4]
  int tt = t / 24576;
  int r = t % 24576;
  int b = r / 384;
  int r3 = r % 384;
  int blk = r3 >> 2;
  int q = r3 & 3;
  unsigned wv = hbf[(size_t)(tt + 1) * SLOT + (size_t)blk * 256 + b * 4 + q];
  int i = blk * 8 + q * 2;
  size_t o = ((size_t)b * 512 + t0 + tt) * 768 + i;
  float lo = __uint_as_float(wv << 16);
  float hi = __uint_as_float(wv & 0xFFFF0000u);
  float2 rv = *(const float2*)(res + o);
  float2 ov = make_float2(lo + rv.x, hi + rv.y);
  *(float2*)(seq + o) = ov;
}

extern "C" void kernel_launch(void* const* d_in, const int* in_sizes, int n_in,
                              void* d_out, int out_size, void* d_ws, size_t ws_size,
                              hipStream_t stream) {
  const float* x    = (const float*)d_in[0];
  const float* h0   = (const float*)d_in[1];
  const float* w_ih = (const float*)d_in[2];
  const float* b_ih = (const float*)d_in[3];
  const float* w_hh = (const float*)d_in[4];
  const float* b_hh = (const float*)d_in[5];
  const float* lnw  = (const float*)d_in[6];
  const float* lnb  = (const float*)d_in[7];
  float* out = (float*)d_out;

  const int B = 64, T = 512, H = 768, G = 2304, L = 2;

  const size_t BAR = 1u << 20;
  int CHUNK = 64;
  for (;;) {
    size_t need = BAR + ((size_t)CHUNK + 1) * 98304 + 196608 + 589824
                + (size_t)B * CHUNK * G * 4;
    if (need <= ws_size || CHUNK == 8) break;
    CHUNK >>= 1;
  }

  unsigned* barctr = (unsigned*)d_ws;
  unsigned* hbf32  = (unsigned*)((char*)d_ws + BAR);
  float* hstate = (float*)((char*)hbf32 + ((size_t)CHUNK + 1) * 98304);
  float* hg     = hstate + 49152;
  float* xg     = hg + 147456;

  hipMemsetAsync(barctr, 0, 65536, stream);

  float* seq  = out;
  float* hfin = out + (size_t)B * T * H;
  const int NCH = T / CHUNK;

  for (int l = 0; l < L; ++l) {
    const float* Wih = w_ih + (size_t)l * G * H;
    const float* Whh = w_hh + (size_t)l * G * H;
    const float* bih = b_ih + (size_t)l * G;
    const float* bhh = b_hh + (size_t)l * G;
    const float* lwp = lnw + (size_t)l * 3 * H;
    const float* lbp = lnb + (size_t)l * 3 * H;
    const float* src = (l == 0) ? x : seq;
    const float* resp = (l == 0) ? x : seq;

    for (int c = 0; c < NCH; ++c) {
      int t0 = c * CHUNK;
      gemm_bt<<<dim3(G / 64, B), 256, 0, stream>>>(
          src + (size_t)t0 * H, (size_t)T * H, Wih, bih,
          xg, (size_t)CHUNK * G, CHUNK);
      const float* hin = (c == 0) ? (h0 + (size_t)l * B * H) : hstate;
      unsigned* barA = barctr + (size_t)(l * NCH + c) * 1024;
      unsigned* barB = barA + 512;
      gru_chunk<<<NWG, 256, 0, stream>>>(
          Whh, bhh, lwp, lbp, xg, CHUNK,
          hin, hstate, hbf32, hg, barA, barB,
          hfin + (size_t)l * B * H, (c == NCH - 1) ? 1 : 0);
      seq_emit<<<CHUNK * 96, 256, 0, stream>>>(hbf32, resp, seq, t0, CHUNK);
    }
  }
}